// Round 1
// baseline (650.610 us; speedup 1.0000x reference)
//
#include <hip/hip_runtime.h>
#include <hip/hip_bf16.h>

// out[n][d] = in[n][d] * W[d]  for fp32 [N=200000, D=512].
// Memory-bound elementwise column-scale. float4-vectorized, grid-stride.
// D/4 = 128 float4 per row -> W4 index = i & 127.

__global__ void Diag_78194174591219_kernel(const float4* __restrict__ in4,
                                           const float4* __restrict__ w4,
                                           float4* __restrict__ out4,
                                           int n4) {
    int i = blockIdx.x * blockDim.x + threadIdx.x;
    const int stride = gridDim.x * blockDim.x;
    for (; i < n4; i += stride) {
        const float4 v = in4[i];
        const float4 w = w4[i & 127];   // D=512 -> 128 float4 per row, L1/L2-resident
        float4 r;
        r.x = v.x * w.x;
        r.y = v.y * w.y;
        r.z = v.z * w.z;
        r.w = v.w * w.w;
        out4[i] = r;
    }
}

extern "C" void kernel_launch(void* const* d_in, const int* in_sizes, int n_in,
                              void* d_out, int out_size, void* d_ws, size_t ws_size,
                              hipStream_t stream) {
    // setup_inputs order: input [200000*512] f32, A [1] f32 (unused), W [512] f32
    const float4* in4 = (const float4*)d_in[0];
    const float4* w4  = (const float4*)d_in[2];
    float4* out4      = (float4*)d_out;

    const int n4 = out_size / 4;  // 25,600,000 float4 elements

    const int block = 256;
    // 256 CUs * 8 blocks/CU = 2048 blocks; grid-stride covers the rest.
    int grid = (n4 + block - 1) / block;
    if (grid > 2048) grid = 2048;

    Diag_78194174591219_kernel<<<grid, block, 0, stream>>>(in4, w4, out4, n4);
}